// Round 12
// baseline (172.289 us; speedup 1.0000x reference)
//
#include <hip/hip_runtime.h>

#define NB 32
#define NT 15

// Workspace layout (byte offsets) — channel-last fire-time maps:
//  ft0  : 0        (B,36,36,18) u8 input ft, pad=2 ring          746496
//  ft1  : 746496   (B,30,30,90) u8 layer-1 ft                   2592000
//  ft2  : 4170816  (B,13,13,250) u8 layer-2 ft                  1352000
//  wT1  : 6034816  (883,90)  f32 w1^T rows j=(r*7+x)*18+c  + 0   317888
//  wT2  : 6352704  (2251,250) f32 w2^T rows j=(r*5+x)*90+c + 0  2251008
//  wT3  : 8603712  (6251,200) f32 w3^T rows j=(r*5+x)*250+c + 0 5000832
//  W3s  : 13605568 (16,200) f32 per-px valid-tap col sums         12800
//  PosS2: 13618368 (25,256) f32 per-position channel sums of w2   25600
//  W2e  : 13643968 (169,256) f32 effective tap-sums (pads excl)  173056
//  Pmin1: 13817024 (64) f32 partial mins of w1                      256
//  m1   : 13817280 (1)  f32 global min of w1                          4
//  zmap : 13817344 (B,36,36) u8 #channels with ft==0              41472
//  PosS3: 13858816 (25,200) f32 per-position channel sums of w3   20000

// ---------- LDS-tiled permuted transpose: dst[j][f] = src[f][k], j=(k%KK)*CIN+k/KK ----------
__device__ __forceinline__ void tr_tile(const float* __restrict__ src, float* __restrict__ dst,
                                        int F, int K, int KK, int CIN, int nkt, int t, int tid) {
    __shared__ float lds[32][33];
    int kt = t % nkt, ft = t / nkt;
    int k0 = kt * 32, f0 = ft * 32;
    int tx = tid & 31, ty = tid >> 5;
#pragma unroll
    for (int i = 0; i < 4; i++) {
        int fl = ty + 8 * i;
        int f = f0 + fl, k = k0 + tx;
        lds[fl][tx] = (f < F && k < K) ? src[(size_t)f * K + k] : 0.f;
    }
    __syncthreads();
#pragma unroll
    for (int i = 0; i < 4; i++) {
        int row = ty + 8 * i;
        int k = k0 + row, f = f0 + tx;
        if (k < K && f < F) {
            int j = (k % KK) * CIN + k / KK;
            dst[(size_t)j * F + f] = lds[tx][row];
        }
    }
}

// ---------- pre1: ft0 (972) + zmap (162) + transposes (2024) + zero rows (1) + w1 mins (40) ----------
__global__ __launch_bounds__(256) void k_pre1(const float* __restrict__ inp,
                                              const float* __restrict__ w1,
                                              const float* __restrict__ w2,
                                              const float* __restrict__ w3,
                                              unsigned char* __restrict__ ft0,
                                              unsigned char* __restrict__ zmap,
                                              float* __restrict__ wT1, float* __restrict__ wT2,
                                              float* __restrict__ wT3,
                                              float* __restrict__ Pmin1) {
    int blk = blockIdx.x, tid = threadIdx.x;
    if (blk < 972) {
        int idx = blk * 256 + tid;              // 972*256 == 32*36*36*6 exactly
        int xx = idx % 36, rest = idx / 36;
        int yy = rest % 36; rest /= 36;
        int g = rest % 6;  int b = rest / 6;
        unsigned char* dst = ft0 + ((size_t)(b * 36 + yy) * 36 + xx) * 18 + g * 3;
        int x = xx - 2, y = yy - 2;
        if (x >= 0 && x < 32 && y >= 0 && y < 32) {
            int c0 = 0, c1 = 0, c2 = 0;
            const float* p = inp + ((size_t)b * NT * 18 + g * 3) * 1024 + y * 32 + x;
#pragma unroll
            for (int t = 0; t < NT; t++) {
                c0 += (p[(size_t)(t * 18 + 0) * 1024] != 0.f);
                c1 += (p[(size_t)(t * 18 + 1) * 1024] != 0.f);
                c2 += (p[(size_t)(t * 18 + 2) * 1024] != 0.f);
            }
            dst[0] = (unsigned char)(15 - c0);
            dst[1] = (unsigned char)(15 - c1);
            dst[2] = (unsigned char)(15 - c2);
        } else {
            dst[0] = 15; dst[1] = 15; dst[2] = 15;
        }
    } else if (blk < 1134) {
        // zmap: ft==0 <=> cumulative input is 1 at t=0
        int idx = (blk - 972) * 256 + tid;      // 162*256 == 41472 exactly
        int xx = idx % 36, rest = idx / 36;
        int yy = rest % 36; int b = rest / 36;
        int x = xx - 2, y = yy - 2;
        int z = 0;
        if (x >= 0 && x < 32 && y >= 0 && y < 32) {
            const float* p = inp + (size_t)b * NT * 18 * 1024 + y * 32 + x;
#pragma unroll
            for (int c = 0; c < 18; c++) z += (p[(size_t)c * 1024] != 0.f);
        }
        zmap[idx] = (unsigned char)z;
    } else if (blk < 3158) {
        const float* src; float* dst;
        int F, K, KK, CIN, nkt, t;
        if (blk < 1218)      { src = w1; dst = wT1; F = 90;  K = 882;  KK = 49; CIN = 18;  nkt = 28;  t = blk - 1134; }
        else if (blk < 1786) { src = w2; dst = wT2; F = 250; K = 2250; KK = 25; CIN = 90;  nkt = 71;  t = blk - 1218; }
        else                 { src = w3; dst = wT3; F = 200; K = 6250; KK = 25; CIN = 250; nkt = 196; t = blk - 1786; }
        tr_tile(src, dst, F, K, KK, CIN, nkt, t, tid);
    } else if (blk == 3158) {
        if (tid < 90)  wT1[882 * 90 + tid] = 0.f;
        if (tid < 250) wT2[(size_t)2250 * 250 + tid] = 0.f;
        if (tid < 200) wT3[(size_t)6250 * 200 + tid] = 0.f;
    } else {
        int bb = blk - 3159;
        __shared__ float wm[4];
        float m = 1e30f;
#pragma unroll
        for (int k = 0; k < 8; k++) {
            int i = bb * 2048 + k * 256 + tid;
            if (i < 90 * 882) m = fminf(m, w1[i]);
        }
        for (int o = 32; o > 0; o >>= 1) m = fminf(m, __shfl_down(m, o));
        if ((tid & 63) == 0) wm[tid >> 6] = m;
        __syncthreads();
        if (tid == 0) Pmin1[bb] = fminf(fminf(wm[0], wm[1]), fminf(wm[2], wm[3]));
    }
}

// ---------- pre2: PosS2 from wT2 (25) + PosS3 from wT3 (25) + m1 finisher (1) ----------
__global__ __launch_bounds__(256) void k_pre2(const float* __restrict__ wT2,
                                              const float* __restrict__ wT3,
                                              const float* __restrict__ Pmin1,
                                              float* __restrict__ PosS2, float* __restrict__ PosS3,
                                              float* __restrict__ m1) {
    int blk = blockIdx.x, tid = threadIdx.x;
    if (blk < 25) {
        int pos = blk;
        int f = tid < 250 ? tid : 249;
        float acc = 0.f;
        for (int c = 0; c < 90; c++) acc += wT2[(size_t)(pos * 90 + c) * 250 + f];
        if (tid < 250) PosS2[pos * 256 + tid] = acc;
    } else if (blk < 50) {
        int pos = blk - 25;
        int f = tid < 200 ? tid : 199;
        float acc = 0.f;
        for (int c = 0; c < 250; c++) acc += wT3[(size_t)(pos * 250 + c) * 200 + f];
        if (tid < 200) PosS3[pos * 200 + tid] = acc;
    } else {
        if (tid < 64) {
            float m = (tid < 40) ? Pmin1[tid] : 1e30f;
            for (int o = 32; o > 0; o >>= 1) m = fminf(m, __shfl_down(m, o));
            if (tid == 0) m1[0] = m;
        }
    }
}

// ---------- pre3: W2e (169) + W3s (16) ----------
__global__ __launch_bounds__(256) void k_pre3(const float* __restrict__ PosS2,
                                              const float* __restrict__ PosS3,
                                              float* __restrict__ W2e, float* __restrict__ W3s) {
    int b = blockIdx.x, tid = threadIdx.x;
    if (b < 169) {
        int f = tid < 250 ? tid : 249;
        int oy = b / 13, ox = b - oy * 13;
        float s = 0.f;
#pragma unroll
        for (int pos = 0; pos < 25; pos++) {
            int r = pos / 5, x = pos - r * 5;
            int gy = oy + r, gx = ox + x;
            if (!(gy == 0 || gy == 16 || gx == 0 || gx == 16)) s += PosS2[pos * 256 + f];
        }
        if (tid < 250) W2e[b * 256 + tid] = s;
    } else {
        int px = b - 169;
        int f = tid < 200 ? tid : 199;
        int oy = px >> 2, ox = px & 3;
        int r0 = max(0, 2 - oy), r1 = min(4, 5 - oy);
        int x0 = max(0, 2 - ox), x1 = min(4, 5 - ox);
        float s = 0.f;
        for (int r = r0; r <= r1; r++)
            for (int x = x0; x <= x1; x++)
                s += PosS3[(r * 5 + x) * 200 + f];
        if (tid < 200) W3s[px * 200 + tid] = s;
    }
}

// ---------- conv1: zmap box-sum bound fast path; exact walk fallback ----------
__global__ __launch_bounds__(128) void k_conv1f(const unsigned char* __restrict__ ft0,
                                                const unsigned char* __restrict__ zmap,
                                                const float* __restrict__ wT1,
                                                const float* __restrict__ m1p,
                                                unsigned char* __restrict__ ft1) {
    __shared__ __align__(16) int list[896];
    __shared__ int cnt, pcnt, cnt0s;
    int tid = threadIdx.x;
    int px = blockIdx.x, b = blockIdx.y;
    int oy = px / 30, ox = px - oy * 30;
    int zv = 0;
    if (tid < 49) zv = zmap[(b * 36 + oy + tid / 7) * 36 + ox + tid % 7];
    if (tid < 64) {
        for (int o = 32; o > 0; o >>= 1) zv += __shfl_down(zv, o);
        if (tid == 0) cnt0s = zv;
    }
    __syncthreads();
    if ((float)cnt0s * m1p[0] > 15.0f) {
        if (tid < 90) ft1[((size_t)(b * 30 + oy) * 30 + ox) * 90 + tid] = 0;
        return;
    }
    const unsigned char* base = ft0 + ((size_t)(b * 36 + oy) * 36 + ox) * 18;
    unsigned char myft[7];
#pragma unroll
    for (int k = 0; k < 7; k++) {
        int j = tid + k * 128;
        if (j < 882) {
            int r = j / 126;
            myft[k] = base[j + 522 * r];
        } else myft[k] = 255;
    }
    int f = tid < 90 ? tid : 89;
    const char* wb = (const char*)(wT1 + f);
    const int zoff = 882 * 90 * 4;
    float acc = 0.f; int ft = 15;
    for (int s = 0; s < 15; s++) {
        if (tid == 0) cnt = 0;
        __syncthreads();
#pragma unroll
        for (int k = 0; k < 7; k++) {
            if ((int)myft[k] == s) { int p = atomicAdd(&cnt, 1); list[p] = (tid + k * 128) * 360; }
        }
        __syncthreads();
        if (tid == 0) {
            int c0 = cnt, cp = (c0 + 7) & ~7;
            for (int i = c0; i < cp; i++) list[i] = zoff;
            pcnt = cp;
        }
        __syncthreads();
        int e = pcnt;
        for (int i = 0; i < e; i += 8) {
            int4 p0 = *(const int4*)(list + i);
            int4 p1 = *(const int4*)(list + i + 4);
            int o0 = __builtin_amdgcn_readfirstlane(p0.x);
            int o1 = __builtin_amdgcn_readfirstlane(p0.y);
            int o2 = __builtin_amdgcn_readfirstlane(p0.z);
            int o3 = __builtin_amdgcn_readfirstlane(p0.w);
            int o4 = __builtin_amdgcn_readfirstlane(p1.x);
            int o5 = __builtin_amdgcn_readfirstlane(p1.y);
            int o6 = __builtin_amdgcn_readfirstlane(p1.z);
            int o7 = __builtin_amdgcn_readfirstlane(p1.w);
            float a0 = *(const float*)(wb + o0);
            float a1 = *(const float*)(wb + o1);
            float a2 = *(const float*)(wb + o2);
            float a3 = *(const float*)(wb + o3);
            float a4 = *(const float*)(wb + o4);
            float a5 = *(const float*)(wb + o5);
            float a6 = *(const float*)(wb + o6);
            float a7 = *(const float*)(wb + o7);
            acc += ((a0 + a1) + (a2 + a3)) + ((a4 + a5) + (a6 + a7));
        }
        if (ft == 15 && acc > 15.0f) ft = s;
        if (__syncthreads_and(ft != 15)) break;
    }
    if (tid < 90) ft1[((size_t)(b * 30 + oy) * 30 + ox) * 90 + tid] = (unsigned char)ft;
}

// ---------- conv2: inline 2x2 pool staging; complement-empty fast path; exact walk ----------
__global__ __launch_bounds__(256) void k_conv2cr(const unsigned char* __restrict__ ft1,
                                                 const float* __restrict__ wT2,
                                                 const float* __restrict__ W2e,
                                                 unsigned char* __restrict__ ft2) {
    constexpr int PADCAP = 2250 + 15 * 8;
    __shared__ __align__(16) int perm[PADCAP];
    __shared__ int start[16], cur[16];
    __shared__ int cntCs;
    int tid = threadIdx.x;
    int px = blockIdx.x, b = blockIdx.y;
    int oy = px / 13, ox = px - oy * 13;
    const unsigned char* fb = ft1 + (size_t)b * 900 * 90;
    if (tid == 0) cntCs = 0;
    if (tid < 16) cur[tid] = 0;
    unsigned char myft[9];
    int nc = 0;
#pragma unroll
    for (int k = 0; k < 9; k++) {
        int j = tid + k * 256;
        myft[k] = 0;
        if (j < 2250) {
            int c = j % 90, pos = j / 90;
            int r = pos / 5, x = pos - r * 5;
            int gy = oy + r, gx = ox + x;        // pooled coords in [0,17)
            if (gy >= 1 && gy <= 15 && gx >= 1 && gx <= 15) {
                const unsigned char* q = fb + ((size_t)((gy - 1) * 2) * 30 + (gx - 1) * 2) * 90 + c;
                int m = q[0];
                m = min(m, (int)q[90]);
                m = min(m, (int)q[2700]);
                m = min(m, (int)q[2790]);
                myft[k] = (unsigned char)m;      // geometric pads stay 0 (W2e contract)
            }
        }
        nc += (myft[k] >= 1);
    }
    for (int o = 32; o > 0; o >>= 1) nc += __shfl_down(nc, o);
    __syncthreads();
    if ((tid & 63) == 0) atomicAdd(&cntCs, nc);
    __syncthreads();
    int f = tid < 250 ? tid : 249;
    float W = W2e[px * 256 + f];
    if (cntCs == 0) {
        if (tid < 250) ft2[((size_t)(b * 13 + oy) * 13 + ox) * 250 + tid] = (W > 10.0f) ? 0 : 15;
        return;
    }
#pragma unroll
    for (int k = 0; k < 9; k++) { int v = myft[k]; if (v >= 1) atomicAdd(&cur[v - 1], 1); }
    __syncthreads();
    if (tid == 0) {
        int s = 0;
#pragma unroll
        for (int j = 0; j < 15; j++) { int c = cur[j]; start[j] = s; s += (c + 7) & ~7; }
        start[15] = s;
    }
    __syncthreads();
    int nnzp = start[15];
    if (tid < 15) cur[tid] = start[tid];
    const int zoff = 2250 * 250 * 4;
    for (int i = tid; i < nnzp; i += 256) perm[i] = zoff;
    __syncthreads();
#pragma unroll
    for (int k = 0; k < 9; k++) {
        int v = myft[k];
        if (v >= 1) { int p = atomicAdd(&cur[v - 1], 1); perm[p] = (tid + k * 256) * 1000; }
    }
    __syncthreads();
    const char* wb = (const char*)(wT2 + f);
    float R = 0.f; int ft = 15;
    for (int j = 14; j >= 0; j--) {
        int sjb = start[j], e = start[j + 1];
        for (int i = sjb; i < e; i += 8) {
            int4 p0 = *(const int4*)(perm + i);
            int4 p1 = *(const int4*)(perm + i + 4);
            int o0 = __builtin_amdgcn_readfirstlane(p0.x);
            int o1 = __builtin_amdgcn_readfirstlane(p0.y);
            int o2 = __builtin_amdgcn_readfirstlane(p0.z);
            int o3 = __builtin_amdgcn_readfirstlane(p0.w);
            int o4 = __builtin_amdgcn_readfirstlane(p1.x);
            int o5 = __builtin_amdgcn_readfirstlane(p1.y);
            int o6 = __builtin_amdgcn_readfirstlane(p1.z);
            int o7 = __builtin_amdgcn_readfirstlane(p1.w);
            float a0 = *(const float*)(wb + o0);
            float a1 = *(const float*)(wb + o1);
            float a2 = *(const float*)(wb + o2);
            float a3 = *(const float*)(wb + o3);
            float a4 = *(const float*)(wb + o4);
            float a5 = *(const float*)(wb + o5);
            float a6 = *(const float*)(wb + o6);
            float a7 = *(const float*)(wb + o7);
            R += ((a0 + a1) + (a2 + a3)) + ((a4 + a5) + (a6 + a7));
        }
        float pot = W - R;
        if (pot > 10.0f) ft = j;
        if (sjb == 0) { if (pot > 10.0f) ft = 0; break; }
        if (__all(pot <= 10.0f)) break;
    }
    if (tid < 250) ft2[((size_t)(b * 13 + oy) * 13 + ox) * 250 + tid] = (unsigned char)ft;
}

// ---------- conv3: inline 3x3 pool staging over VALID taps; stores all 15 pots ----------
__global__ __launch_bounds__(256) void k_conv3cr(const unsigned char* __restrict__ ft2,
                                                 const float* __restrict__ wT3,
                                                 const float* __restrict__ W3s,
                                                 float* __restrict__ out) {
    constexpr int PADCAP = 4000 + 15 * 8;
    __shared__ __align__(16) int perm[PADCAP];
    __shared__ int start[16], cur[16];
    __shared__ int offs[16], rowb[16];
    int tid = threadIdx.x;
    int px = blockIdx.x, b = blockIdx.y;
    int oy = px >> 2, ox = px & 3;
    int r0 = max(0, 2 - oy), r1 = min(4, 5 - oy);
    int x0 = max(0, 2 - ox), x1 = min(4, 5 - ox);
    int VR = r1 - r0 + 1, VC = x1 - x0 + 1;
    int NP = VR * VC, NV = NP * 250;
    if (tid < NP) {
        int rv = tid / VC, xv = tid - rv * VC;
        int py = oy + r0 + rv, gx = ox + x0 + xv;        // pooled coords in [2,6)
        offs[tid] = (((py - 2) * 3) * 13 + (gx - 2) * 3) * 250;  // ft2 3x3 top-left
        rowb[tid] = ((r0 + rv) * 5 + (x0 + xv)) * 250;
    }
    if (tid < 16) cur[tid] = 0;
    const unsigned char* base2 = ft2 + (size_t)b * 169 * 250;
    __syncthreads();
    unsigned char myft[16];
#pragma unroll
    for (int k = 0; k < 16; k++) {
        int i = tid + k * 256;
        myft[k] = 0;
        if (i < NV) {
            int posv = i / 250, c = i - posv * 250;
            const unsigned char* q = base2 + offs[posv] + c;
            int m = q[0];
            m = min(m, (int)q[250]);  m = min(m, (int)q[500]);
            m = min(m, (int)q[3250]); m = min(m, (int)q[3500]); m = min(m, (int)q[3750]);
            m = min(m, (int)q[6500]); m = min(m, (int)q[6750]); m = min(m, (int)q[7000]);
            myft[k] = (unsigned char)m;
        }
    }
#pragma unroll
    for (int k = 0; k < 16; k++) { int v = myft[k]; if (v >= 1) atomicAdd(&cur[v - 1], 1); }
    __syncthreads();
    if (tid == 0) {
        int s = 0;
#pragma unroll
        for (int j = 0; j < 15; j++) { int c = cur[j]; start[j] = s; s += (c + 7) & ~7; }
        start[15] = s;
    }
    __syncthreads();
    int nnzp = start[15];
    if (tid < 15) cur[tid] = start[tid];
    const int zoff = 6250 * 200 * 4;
    for (int i = tid; i < nnzp; i += 256) perm[i] = zoff;
    __syncthreads();
#pragma unroll
    for (int k = 0; k < 16; k++) {
        int v = myft[k];
        if (v >= 1) {
            int i = tid + k * 256;
            int posv = i / 250, c = i - posv * 250;
            int p = atomicAdd(&cur[v - 1], 1);
            perm[p] = (rowb[posv] + c) * 800;
        }
    }
    __syncthreads();

    int f = tid < 200 ? tid : 199;
    const char* wb = (const char*)(wT3 + f);
    float W = W3s[px * 200 + f];
    float* o = out + 32 + ((size_t)b * NT) * 3200 + f * 16 + px;
    float R = 0.f;
    for (int j = 14; j >= 0; j--) {
        int sjb = start[j], e = start[j + 1];
        for (int i = sjb; i < e; i += 8) {
            int4 p0 = *(const int4*)(perm + i);
            int4 p1 = *(const int4*)(perm + i + 4);
            int o0 = __builtin_amdgcn_readfirstlane(p0.x);
            int o1 = __builtin_amdgcn_readfirstlane(p0.y);
            int o2 = __builtin_amdgcn_readfirstlane(p0.z);
            int o3 = __builtin_amdgcn_readfirstlane(p0.w);
            int o4 = __builtin_amdgcn_readfirstlane(p1.x);
            int o5 = __builtin_amdgcn_readfirstlane(p1.y);
            int o6 = __builtin_amdgcn_readfirstlane(p1.z);
            int o7 = __builtin_amdgcn_readfirstlane(p1.w);
            float a0 = *(const float*)(wb + o0);
            float a1 = *(const float*)(wb + o1);
            float a2 = *(const float*)(wb + o2);
            float a3 = *(const float*)(wb + o3);
            float a4 = *(const float*)(wb + o4);
            float a5 = *(const float*)(wb + o5);
            float a6 = *(const float*)(wb + o6);
            float a7 = *(const float*)(wb + o7);
            R += ((a0 + a1) + (a2 + a3)) + ((a4 + a5) + (a6 + a7));
        }
        float pot = W - R;
        if (tid < 200) o[(size_t)j * 3200] = pot;
        if (sjb == 0) {
            for (int jj = j - 1; jj >= 0; jj--)
                if (tid < 200) o[(size_t)jj * 3200] = pot;
            break;
        }
    }
}

// ---------- winner-take-all classification ----------
__global__ __launch_bounds__(256) void k_winner(const float* __restrict__ outp,
                                                float* __restrict__ outc) {
    int b = blockIdx.x, tid = threadIdx.x;
    const float* p14 = outp + 32 + ((size_t)b * NT + 14) * 3200;
    __shared__ float sv[256];
    __shared__ int   si[256];
    float m = 0.f;
    for (int j = tid; j < 3200; j += 256) {
        float v = p14[j];
        if (v > 0.f && v > m) m = v;
    }
    sv[tid] = m;
    __syncthreads();
    for (int s = 128; s > 0; s >>= 1) {
        if (tid < s) sv[tid] = fmaxf(sv[tid], sv[tid + s]);
        __syncthreads();
    }
    float vofs = 15.f * sv[0];
    __syncthreads();
    float bestv = 0.f; int besti = 0x3fffffff;
    for (int j = tid; j < 3200; j += 256) {
        float v = p14[j];
        float tot = (v > 0.f) ? v + vofs : 0.f;
        if (tot > bestv) { bestv = tot; besti = j; }
    }
    sv[tid] = bestv; si[tid] = besti;
    __syncthreads();
    for (int s = 128; s > 0; s >>= 1) {
        if (tid < s) {
            if (sv[tid + s] > sv[tid] || (sv[tid + s] == sv[tid] && si[tid + s] < si[tid])) {
                sv[tid] = sv[tid + s]; si[tid] = si[tid + s];
            }
        }
        __syncthreads();
    }
    if (tid == 0) {
        float mx = sv[0];
        int cls = (mx != 0.f) ? ((si[0] / 16) / 20) : -1;
        outc[b] = (float)cls;
    }
}

extern "C" void kernel_launch(void* const* d_in, const int* in_sizes, int n_in,
                              void* d_out, int out_size, void* d_ws, size_t ws_size,
                              hipStream_t stream) {
    const float* inp = (const float*)d_in[0];
    const float* w1  = (const float*)d_in[1];
    const float* w2  = (const float*)d_in[2];
    const float* w3  = (const float*)d_in[3];
    float* out = (float*)d_out;

    unsigned char* ws   = (unsigned char*)d_ws;
    unsigned char* ft0  = ws;
    unsigned char* ft1  = ws + 746496;
    unsigned char* ft2  = ws + 4170816;
    float* wT1   = (float*)(ws + 6034816);
    float* wT2   = (float*)(ws + 6352704);
    float* wT3   = (float*)(ws + 8603712);
    float* W3s   = (float*)(ws + 13605568);
    float* PosS2 = (float*)(ws + 13618368);
    float* W2e   = (float*)(ws + 13643968);
    float* Pmin1 = (float*)(ws + 13817024);
    float* m1    = (float*)(ws + 13817280);
    unsigned char* zmap = ws + 13817344;
    float* PosS3 = (float*)(ws + 13858816);

    hipLaunchKernelGGL(k_pre1, dim3(3199), dim3(256), 0, stream,
                       inp, w1, w2, w3, ft0, zmap, wT1, wT2, wT3, Pmin1);
    hipLaunchKernelGGL(k_pre2, dim3(51), dim3(256), 0, stream, wT2, wT3, Pmin1, PosS2, PosS3, m1);
    hipLaunchKernelGGL(k_pre3, dim3(185), dim3(256), 0, stream, PosS2, PosS3, W2e, W3s);

    hipLaunchKernelGGL(k_conv1f, dim3(900, NB), dim3(128), 0, stream, ft0, zmap, wT1, m1, ft1);
    hipLaunchKernelGGL(k_conv2cr, dim3(169, NB), dim3(256), 0, stream, ft1, wT2, W2e, ft2);
    hipLaunchKernelGGL(k_conv3cr, dim3(16, NB), dim3(256), 0, stream, ft2, wT3, W3s, out);
    hipLaunchKernelGGL(k_winner, dim3(NB), dim3(256), 0, stream, out, out);
}

// Round 13
// 161.170 us; speedup vs baseline: 1.0690x; 1.0690x over previous
//
#include <hip/hip_runtime.h>

#define NB 32
#define NT 15

// Workspace layout (byte offsets) — channel-last fire-time maps:
//  ft0  : 0        (B,36,36,18) u8 input ft, pad=2 ring          746496
//  ft1  : 746496   (B,30,30,90) u8 layer-1 ft                   2592000
//  ft1p : 3338496  (B,17,17,90) u8 pool2x2s2, pad ring = 0       832320
//  ft2  : 4170816  (B,13,13,250) u8 layer-2 ft                  1352000
//  ft2p : 5522816  (B,8,8,250)  u8 pool3x3s3 + pad=2             512000
//  wT1  : 6034816  (883,90)  f32 w1^T rows j=(r*7+x)*18+c  + 0   317888
//  wT2  : 6352704  (2251,250) f32 w2^T rows j=(r*5+x)*90+c + 0  2251008
//  wT3  : 8603712  (6251,200) f32 w3^T rows j=(r*5+x)*250+c + 0 5000832
//  W3s  : 13605568 (16,200) f32 per-px valid-tap col sums         12800
//  PosS2: 13618368 (25,256) f32 per-position channel sums of w2   25600
//  W2e  : 13643968 (169,256) f32 effective tap-sums (pads excl)  173056
//  Pmin1: 13817024 (64) f32 partial mins of w1                      256
//  m1   : 13817280 (1)  f32 global min of w1                          4
//  zmap : 13817344 (B,36,36) u8 #channels with ft==0              41472
//  PosS3: 13858816 (25,200) f32 per-position channel sums of w3   20000

// ---------- LDS-tiled permuted transpose: dst[j][f] = src[f][k], j=(k%KK)*CIN+k/KK ----------
__device__ __forceinline__ void tr_tile(const float* __restrict__ src, float* __restrict__ dst,
                                        int F, int K, int KK, int CIN, int nkt, int t, int tid) {
    __shared__ float lds[32][33];
    int kt = t % nkt, ft = t / nkt;
    int k0 = kt * 32, f0 = ft * 32;
    int tx = tid & 31, ty = tid >> 5;
#pragma unroll
    for (int i = 0; i < 4; i++) {
        int fl = ty + 8 * i;
        int f = f0 + fl, k = k0 + tx;
        lds[fl][tx] = (f < F && k < K) ? src[(size_t)f * K + k] : 0.f;
    }
    __syncthreads();
#pragma unroll
    for (int i = 0; i < 4; i++) {
        int row = ty + 8 * i;
        int k = k0 + row, f = f0 + tx;
        if (k < K && f < F) {
            int j = (k % KK) * CIN + k / KK;
            dst[(size_t)j * F + f] = lds[tx][row];
        }
    }
}

// ---------- pre1: ft0 (972) + tiled transposes (84+568+1372) + zero rows (1) + w1 mins (40) ----------
__global__ __launch_bounds__(256) void k_pre1(const float* __restrict__ inp,
                                              const float* __restrict__ w1,
                                              const float* __restrict__ w2,
                                              const float* __restrict__ w3,
                                              unsigned char* __restrict__ ft0,
                                              float* __restrict__ wT1, float* __restrict__ wT2,
                                              float* __restrict__ wT3,
                                              float* __restrict__ Pmin1) {
    int blk = blockIdx.x, tid = threadIdx.x;
    if (blk < 972) {
        int idx = blk * 256 + tid;              // 972*256 == 32*36*36*6 exactly
        int xx = idx % 36, rest = idx / 36;
        int yy = rest % 36; rest /= 36;
        int g = rest % 6;  int b = rest / 6;
        unsigned char* dst = ft0 + ((size_t)(b * 36 + yy) * 36 + xx) * 18 + g * 3;
        int x = xx - 2, y = yy - 2;
        if (x >= 0 && x < 32 && y >= 0 && y < 32) {
            int c0 = 0, c1 = 0, c2 = 0;
            const float* p = inp + ((size_t)b * NT * 18 + g * 3) * 1024 + y * 32 + x;
#pragma unroll
            for (int t = 0; t < NT; t++) {
                c0 += (p[(size_t)(t * 18 + 0) * 1024] != 0.f);
                c1 += (p[(size_t)(t * 18 + 1) * 1024] != 0.f);
                c2 += (p[(size_t)(t * 18 + 2) * 1024] != 0.f);
            }
            dst[0] = (unsigned char)(15 - c0);
            dst[1] = (unsigned char)(15 - c1);
            dst[2] = (unsigned char)(15 - c2);
        } else {
            dst[0] = 15; dst[1] = 15; dst[2] = 15;
        }
    } else if (blk < 2996) {
        const float* src; float* dst;
        int F, K, KK, CIN, nkt, t;
        if (blk < 1056)      { src = w1; dst = wT1; F = 90;  K = 882;  KK = 49; CIN = 18;  nkt = 28;  t = blk - 972; }
        else if (blk < 1624) { src = w2; dst = wT2; F = 250; K = 2250; KK = 25; CIN = 90;  nkt = 71;  t = blk - 1056; }
        else                 { src = w3; dst = wT3; F = 200; K = 6250; KK = 25; CIN = 250; nkt = 196; t = blk - 1624; }
        tr_tile(src, dst, F, K, KK, CIN, nkt, t, tid);
    } else if (blk == 2996) {
        if (tid < 90)  wT1[882 * 90 + tid] = 0.f;
        if (tid < 250) wT2[(size_t)2250 * 250 + tid] = 0.f;
        if (tid < 200) wT3[(size_t)6250 * 200 + tid] = 0.f;
    } else {
        int bb = blk - 2997;
        __shared__ float wm[4];
        float m = 1e30f;
#pragma unroll
        for (int k = 0; k < 8; k++) {
            int i = bb * 2048 + k * 256 + tid;
            if (i < 90 * 882) m = fminf(m, w1[i]);
        }
        for (int o = 32; o > 0; o >>= 1) m = fminf(m, __shfl_down(m, o));
        if ((tid & 63) == 0) wm[tid >> 6] = m;
        __syncthreads();
        if (tid == 0) Pmin1[bb] = fminf(fminf(wm[0], wm[1]), fminf(wm[2], wm[3]));
    }
}

// ---------- pre2: zmap (162) + PosS2 from wT2 (25) + PosS3 from wT3 (25) + m1 finisher (1) ----------
__global__ __launch_bounds__(256) void k_pre2(const unsigned char* __restrict__ ft0,
                                              const float* __restrict__ wT2,
                                              const float* __restrict__ wT3,
                                              const float* __restrict__ Pmin1,
                                              unsigned char* __restrict__ zmap,
                                              float* __restrict__ PosS2, float* __restrict__ PosS3,
                                              float* __restrict__ m1) {
    int blk = blockIdx.x, tid = threadIdx.x;
    if (blk < 162) {
        int idx = blk * 256 + tid;              // 41472 exactly
        const unsigned char* p = ft0 + (size_t)idx * 18;
        int z = 0;
#pragma unroll
        for (int c = 0; c < 18; c++) z += (p[c] == 0);
        zmap[idx] = (unsigned char)z;
    } else if (blk < 187) {
        int pos = blk - 162;
        int f = tid < 250 ? tid : 249;
        float acc = 0.f;
        for (int c = 0; c < 90; c++) acc += wT2[(size_t)(pos * 90 + c) * 250 + f];
        if (tid < 250) PosS2[pos * 256 + tid] = acc;
    } else if (blk < 212) {
        int pos = blk - 187;
        int f = tid < 200 ? tid : 199;
        float acc = 0.f;
        for (int c = 0; c < 250; c++) acc += wT3[(size_t)(pos * 250 + c) * 200 + f];
        if (tid < 200) PosS3[pos * 200 + tid] = acc;
    } else {
        if (tid < 64) {
            float m = (tid < 40) ? Pmin1[tid] : 1e30f;
            for (int o = 32; o > 0; o >>= 1) m = fminf(m, __shfl_down(m, o));
            if (tid == 0) m1[0] = m;
        }
    }
}

// ---------- pre3: W2e (169) + W3s (16) ----------
__global__ __launch_bounds__(256) void k_pre3(const float* __restrict__ PosS2,
                                              const float* __restrict__ PosS3,
                                              float* __restrict__ W2e, float* __restrict__ W3s) {
    int b = blockIdx.x, tid = threadIdx.x;
    if (b < 169) {
        int f = tid < 250 ? tid : 249;
        int oy = b / 13, ox = b - oy * 13;
        float s = 0.f;
#pragma unroll
        for (int pos = 0; pos < 25; pos++) {
            int r = pos / 5, x = pos - r * 5;
            int gy = oy + r, gx = ox + x;
            if (!(gy == 0 || gy == 16 || gx == 0 || gx == 16)) s += PosS2[pos * 256 + f];
        }
        if (tid < 250) W2e[b * 256 + tid] = s;
    } else {
        int px = b - 169;
        int f = tid < 200 ? tid : 199;
        int oy = px >> 2, ox = px & 3;
        int r0 = max(0, 2 - oy), r1 = min(4, 5 - oy);
        int x0 = max(0, 2 - ox), x1 = min(4, 5 - ox);
        float s = 0.f;
        for (int r = r0; r <= r1; r++)
            for (int x = x0; x <= x1; x++)
                s += PosS3[(r * 5 + x) * 200 + f];
        if (tid < 200) W3s[px * 200 + tid] = s;
    }
}

// ---------- conv1: zmap box-sum bound fast path; exact walk fallback ----------
__global__ __launch_bounds__(128) void k_conv1f(const unsigned char* __restrict__ ft0,
                                                const unsigned char* __restrict__ zmap,
                                                const float* __restrict__ wT1,
                                                const float* __restrict__ m1p,
                                                unsigned char* __restrict__ ft1) {
    __shared__ __align__(16) int list[896];
    __shared__ int cnt, pcnt, cnt0s;
    int tid = threadIdx.x;
    int px = blockIdx.x, b = blockIdx.y;
    int oy = px / 30, ox = px - oy * 30;
    int zv = 0;
    if (tid < 49) zv = zmap[(b * 36 + oy + tid / 7) * 36 + ox + tid % 7];
    if (tid < 64) {
        for (int o = 32; o > 0; o >>= 1) zv += __shfl_down(zv, o);
        if (tid == 0) cnt0s = zv;
    }
    __syncthreads();
    if ((float)cnt0s * m1p[0] > 15.0f) {
        if (tid < 90) ft1[((size_t)(b * 30 + oy) * 30 + ox) * 90 + tid] = 0;
        return;
    }
    const unsigned char* base = ft0 + ((size_t)(b * 36 + oy) * 36 + ox) * 18;
    unsigned char myft[7];
#pragma unroll
    for (int k = 0; k < 7; k++) {
        int j = tid + k * 128;
        if (j < 882) {
            int r = j / 126;
            myft[k] = base[j + 522 * r];
        } else myft[k] = 255;
    }
    int f = tid < 90 ? tid : 89;
    const char* wb = (const char*)(wT1 + f);
    const int zoff = 882 * 90 * 4;
    float acc = 0.f; int ft = 15;
    for (int s = 0; s < 15; s++) {
        if (tid == 0) cnt = 0;
        __syncthreads();
#pragma unroll
        for (int k = 0; k < 7; k++) {
            if ((int)myft[k] == s) { int p = atomicAdd(&cnt, 1); list[p] = (tid + k * 128) * 360; }
        }
        __syncthreads();
        if (tid == 0) {
            int c0 = cnt, cp = (c0 + 7) & ~7;
            for (int i = c0; i < cp; i++) list[i] = zoff;
            pcnt = cp;
        }
        __syncthreads();
        int e = pcnt;
        for (int i = 0; i < e; i += 8) {
            int4 p0 = *(const int4*)(list + i);
            int4 p1 = *(const int4*)(list + i + 4);
            int o0 = __builtin_amdgcn_readfirstlane(p0.x);
            int o1 = __builtin_amdgcn_readfirstlane(p0.y);
            int o2 = __builtin_amdgcn_readfirstlane(p0.z);
            int o3 = __builtin_amdgcn_readfirstlane(p0.w);
            int o4 = __builtin_amdgcn_readfirstlane(p1.x);
            int o5 = __builtin_amdgcn_readfirstlane(p1.y);
            int o6 = __builtin_amdgcn_readfirstlane(p1.z);
            int o7 = __builtin_amdgcn_readfirstlane(p1.w);
            float a0 = *(const float*)(wb + o0);
            float a1 = *(const float*)(wb + o1);
            float a2 = *(const float*)(wb + o2);
            float a3 = *(const float*)(wb + o3);
            float a4 = *(const float*)(wb + o4);
            float a5 = *(const float*)(wb + o5);
            float a6 = *(const float*)(wb + o6);
            float a7 = *(const float*)(wb + o7);
            acc += ((a0 + a1) + (a2 + a3)) + ((a4 + a5) + (a6 + a7));
        }
        if (ft == 15 && acc > 15.0f) ft = s;
        if (__syncthreads_and(ft != 15)) break;
    }
    if (tid < 90) ft1[((size_t)(b * 30 + oy) * 30 + ox) * 90 + tid] = (unsigned char)ft;
}

// ---------- conv2: complement-empty fast path; exact walk fallback ----------
__global__ __launch_bounds__(256) void k_conv2cr(const unsigned char* __restrict__ ft1p,
                                                 const float* __restrict__ wT2,
                                                 const float* __restrict__ W2e,
                                                 unsigned char* __restrict__ ft2) {
    constexpr int PADCAP = 2250 + 15 * 8;
    __shared__ __align__(16) int perm[PADCAP];
    __shared__ int start[16], cur[16];
    __shared__ int cntCs;
    int tid = threadIdx.x;
    int px = blockIdx.x, b = blockIdx.y;
    int oy = px / 13, ox = px - oy * 13;
    const unsigned char* base = ft1p + ((size_t)(b * 17 + oy) * 17 + ox) * 90;
    if (tid == 0) cntCs = 0;
    if (tid < 16) cur[tid] = 0;
    unsigned char myft[9];
    int nc = 0;
#pragma unroll
    for (int k = 0; k < 9; k++) {
        int j = tid + k * 256;
        myft[k] = 0;
        if (j < 2250) {
            int r = j / 450;
            myft[k] = base[j + 1080 * r];
        }
        nc += (myft[k] >= 1);
    }
    for (int o = 32; o > 0; o >>= 1) nc += __shfl_down(nc, o);
    __syncthreads();
    if ((tid & 63) == 0) atomicAdd(&cntCs, nc);
    __syncthreads();
    int f = tid < 250 ? tid : 249;
    float W = W2e[px * 256 + f];
    if (cntCs == 0) {
        if (tid < 250) ft2[((size_t)(b * 13 + oy) * 13 + ox) * 250 + tid] = (W > 10.0f) ? 0 : 15;
        return;
    }
#pragma unroll
    for (int k = 0; k < 9; k++) { int v = myft[k]; if (v >= 1) atomicAdd(&cur[v - 1], 1); }
    __syncthreads();
    if (tid == 0) {
        int s = 0;
#pragma unroll
        for (int j = 0; j < 15; j++) { int c = cur[j]; start[j] = s; s += (c + 7) & ~7; }
        start[15] = s;
    }
    __syncthreads();
    int nnzp = start[15];
    if (tid < 15) cur[tid] = start[tid];
    const int zoff = 2250 * 250 * 4;
    for (int i = tid; i < nnzp; i += 256) perm[i] = zoff;
    __syncthreads();
#pragma unroll
    for (int k = 0; k < 9; k++) {
        int v = myft[k];
        if (v >= 1) { int p = atomicAdd(&cur[v - 1], 1); perm[p] = (tid + k * 256) * 1000; }
    }
    __syncthreads();
    const char* wb = (const char*)(wT2 + f);
    float R = 0.f; int ft = 15;
    for (int j = 14; j >= 0; j--) {
        int sjb = start[j], e = start[j + 1];
        for (int i = sjb; i < e; i += 8) {
            int4 p0 = *(const int4*)(perm + i);
            int4 p1 = *(const int4*)(perm + i + 4);
            int o0 = __builtin_amdgcn_readfirstlane(p0.x);
            int o1 = __builtin_amdgcn_readfirstlane(p0.y);
            int o2 = __builtin_amdgcn_readfirstlane(p0.z);
            int o3 = __builtin_amdgcn_readfirstlane(p0.w);
            int o4 = __builtin_amdgcn_readfirstlane(p1.x);
            int o5 = __builtin_amdgcn_readfirstlane(p1.y);
            int o6 = __builtin_amdgcn_readfirstlane(p1.z);
            int o7 = __builtin_amdgcn_readfirstlane(p1.w);
            float a0 = *(const float*)(wb + o0);
            float a1 = *(const float*)(wb + o1);
            float a2 = *(const float*)(wb + o2);
            float a3 = *(const float*)(wb + o3);
            float a4 = *(const float*)(wb + o4);
            float a5 = *(const float*)(wb + o5);
            float a6 = *(const float*)(wb + o6);
            float a7 = *(const float*)(wb + o7);
            R += ((a0 + a1) + (a2 + a3)) + ((a4 + a5) + (a6 + a7));
        }
        float pot = W - R;
        if (pot > 10.0f) ft = j;
        if (sjb == 0) { if (pot > 10.0f) ft = 0; break; }
        if (__all(pot <= 10.0f)) break;
    }
    if (tid < 250) ft2[((size_t)(b * 13 + oy) * 13 + ox) * 250 + tid] = (unsigned char)ft;
}

// ---------- conv3 complement walk over VALID taps; stores all 15 pots ----------
__global__ __launch_bounds__(256) void k_conv3cr(const unsigned char* __restrict__ ft2p,
                                                 const float* __restrict__ wT3,
                                                 const float* __restrict__ W3s,
                                                 float* __restrict__ out) {
    constexpr int PADCAP = 4000 + 15 * 8;
    __shared__ __align__(16) int perm[PADCAP];
    __shared__ int start[16], cur[16];
    __shared__ int offs[16], rowb[16];
    int tid = threadIdx.x;
    int px = blockIdx.x, b = blockIdx.y;
    int oy = px >> 2, ox = px & 3;
    int r0 = max(0, 2 - oy), r1 = min(4, 5 - oy);
    int x0 = max(0, 2 - ox), x1 = min(4, 5 - ox);
    int VR = r1 - r0 + 1, VC = x1 - x0 + 1;
    int NP = VR * VC, NV = NP * 250;
    if (tid < NP) {
        int rv = tid / VC, xv = tid - rv * VC;
        offs[tid] = ((r0 + rv) * 8 + (x0 + xv)) * 250;
        rowb[tid] = ((r0 + rv) * 5 + (x0 + xv)) * 250;
    }
    if (tid < 16) cur[tid] = 0;
    const unsigned char* base = ft2p + ((size_t)(b * 8 + oy) * 8 + ox) * 250;
    __syncthreads();
    unsigned char myft[16];
#pragma unroll
    for (int k = 0; k < 16; k++) {
        int i = tid + k * 256;
        myft[k] = 0;
        if (i < NV) {
            int posv = i / 250, c = i - posv * 250;
            myft[k] = base[offs[posv] + c];
        }
    }
#pragma unroll
    for (int k = 0; k < 16; k++) { int v = myft[k]; if (v >= 1) atomicAdd(&cur[v - 1], 1); }
    __syncthreads();
    if (tid == 0) {
        int s = 0;
#pragma unroll
        for (int j = 0; j < 15; j++) { int c = cur[j]; start[j] = s; s += (c + 7) & ~7; }
        start[15] = s;
    }
    __syncthreads();
    int nnzp = start[15];
    if (tid < 15) cur[tid] = start[tid];
    const int zoff = 6250 * 200 * 4;
    for (int i = tid; i < nnzp; i += 256) perm[i] = zoff;
    __syncthreads();
#pragma unroll
    for (int k = 0; k < 16; k++) {
        int v = myft[k];
        if (v >= 1) {
            int i = tid + k * 256;
            int posv = i / 250, c = i - posv * 250;
            int p = atomicAdd(&cur[v - 1], 1);
            perm[p] = (rowb[posv] + c) * 800;
        }
    }
    __syncthreads();

    int f = tid < 200 ? tid : 199;
    const char* wb = (const char*)(wT3 + f);
    float W = W3s[px * 200 + f];
    float* o = out + 32 + ((size_t)b * NT) * 3200 + f * 16 + px;
    float R = 0.f;
    for (int j = 14; j >= 0; j--) {
        int sjb = start[j], e = start[j + 1];
        for (int i = sjb; i < e; i += 8) {
            int4 p0 = *(const int4*)(perm + i);
            int4 p1 = *(const int4*)(perm + i + 4);
            int o0 = __builtin_amdgcn_readfirstlane(p0.x);
            int o1 = __builtin_amdgcn_readfirstlane(p0.y);
            int o2 = __builtin_amdgcn_readfirstlane(p0.z);
            int o3 = __builtin_amdgcn_readfirstlane(p0.w);
            int o4 = __builtin_amdgcn_readfirstlane(p1.x);
            int o5 = __builtin_amdgcn_readfirstlane(p1.y);
            int o6 = __builtin_amdgcn_readfirstlane(p1.z);
            int o7 = __builtin_amdgcn_readfirstlane(p1.w);
            float a0 = *(const float*)(wb + o0);
            float a1 = *(const float*)(wb + o1);
            float a2 = *(const float*)(wb + o2);
            float a3 = *(const float*)(wb + o3);
            float a4 = *(const float*)(wb + o4);
            float a5 = *(const float*)(wb + o5);
            float a6 = *(const float*)(wb + o6);
            float a7 = *(const float*)(wb + o7);
            R += ((a0 + a1) + (a2 + a3)) + ((a4 + a5) + (a6 + a7));
        }
        float pot = W - R;
        if (tid < 200) o[(size_t)j * 3200] = pot;
        if (sjb == 0) {
            for (int jj = j - 1; jj >= 0; jj--)
                if (tid < 200) o[(size_t)jj * 3200] = pot;
            break;
        }
    }
}

// ---------- pool 2x2 s2 (min ft); pad ring = 0 (pads excluded via W2e) ----------
__global__ __launch_bounds__(256) void k_pool1c(const unsigned char* __restrict__ ft1,
                                                unsigned char* __restrict__ ft1p) {
    int idx = blockIdx.x * 256 + threadIdx.x;
    if (idx >= NB * 17 * 17 * 90) return;
    int c = idx % 90, rest = idx / 90;
    int xx = rest % 17; rest /= 17;
    int yy = rest % 17; int b = rest / 17;
    int ft = 0;
    if (xx >= 1 && xx < 16 && yy >= 1 && yy < 16) {
        const unsigned char* p = ft1 + ((size_t)(b * 30 + (yy - 1) * 2) * 30 + (xx - 1) * 2) * 90 + c;
        int m = p[0];
        m = min(m, (int)p[90]);
        m = min(m, (int)p[30 * 90]);
        m = min(m, (int)p[31 * 90]);
        ft = m;
    }
    ft1p[idx] = (unsigned char)ft;
}

// ---------- pool 3x3 s3 (min ft) + pad=2 (pads never read by conv3) ----------
__global__ __launch_bounds__(256) void k_pool2c(const unsigned char* __restrict__ ft2,
                                                unsigned char* __restrict__ ft2p) {
    int idx = blockIdx.x * 256 + threadIdx.x;
    if (idx >= NB * 8 * 8 * 250) return;
    int c = idx % 250, rest = idx / 250;
    int xx = rest % 8; rest /= 8;
    int yy = rest % 8; int b = rest / 8;
    int ft = 15;
    if (xx >= 2 && xx < 6 && yy >= 2 && yy < 6) {
        const unsigned char* p = ft2 + ((size_t)(b * 13 + (yy - 2) * 3) * 13 + (xx - 2) * 3) * 250 + c;
        int m = 15;
#pragma unroll
        for (int dy = 0; dy < 3; dy++)
#pragma unroll
            for (int dx = 0; dx < 3; dx++) m = min(m, (int)p[(dy * 13 + dx) * 250]);
        ft = m;
    }
    ft2p[idx] = (unsigned char)ft;
}

// ---------- winner-take-all classification ----------
__global__ __launch_bounds__(256) void k_winner(const float* __restrict__ outp,
                                                float* __restrict__ outc) {
    int b = blockIdx.x, tid = threadIdx.x;
    const float* p14 = outp + 32 + ((size_t)b * NT + 14) * 3200;
    __shared__ float sv[256];
    __shared__ int   si[256];
    float m = 0.f;
    for (int j = tid; j < 3200; j += 256) {
        float v = p14[j];
        if (v > 0.f && v > m) m = v;
    }
    sv[tid] = m;
    __syncthreads();
    for (int s = 128; s > 0; s >>= 1) {
        if (tid < s) sv[tid] = fmaxf(sv[tid], sv[tid + s]);
        __syncthreads();
    }
    float vofs = 15.f * sv[0];
    __syncthreads();
    float bestv = 0.f; int besti = 0x3fffffff;
    for (int j = tid; j < 3200; j += 256) {
        float v = p14[j];
        float tot = (v > 0.f) ? v + vofs : 0.f;
        if (tot > bestv) { bestv = tot; besti = j; }
    }
    sv[tid] = bestv; si[tid] = besti;
    __syncthreads();
    for (int s = 128; s > 0; s >>= 1) {
        if (tid < s) {
            if (sv[tid + s] > sv[tid] || (sv[tid + s] == sv[tid] && si[tid + s] < si[tid])) {
                sv[tid] = sv[tid + s]; si[tid] = si[tid + s];
            }
        }
        __syncthreads();
    }
    if (tid == 0) {
        float mx = sv[0];
        int cls = (mx != 0.f) ? ((si[0] / 16) / 20) : -1;
        outc[b] = (float)cls;
    }
}

extern "C" void kernel_launch(void* const* d_in, const int* in_sizes, int n_in,
                              void* d_out, int out_size, void* d_ws, size_t ws_size,
                              hipStream_t stream) {
    const float* inp = (const float*)d_in[0];
    const float* w1  = (const float*)d_in[1];
    const float* w2  = (const float*)d_in[2];
    const float* w3  = (const float*)d_in[3];
    float* out = (float*)d_out;

    unsigned char* ws   = (unsigned char*)d_ws;
    unsigned char* ft0  = ws;
    unsigned char* ft1  = ws + 746496;
    unsigned char* ft1p = ws + 3338496;
    unsigned char* ft2  = ws + 4170816;
    unsigned char* ft2p = ws + 5522816;
    float* wT1   = (float*)(ws + 6034816);
    float* wT2   = (float*)(ws + 6352704);
    float* wT3   = (float*)(ws + 8603712);
    float* W3s   = (float*)(ws + 13605568);
    float* PosS2 = (float*)(ws + 13618368);
    float* W2e   = (float*)(ws + 13643968);
    float* Pmin1 = (float*)(ws + 13817024);
    float* m1    = (float*)(ws + 13817280);
    unsigned char* zmap = ws + 13817344;
    float* PosS3 = (float*)(ws + 13858816);

    hipLaunchKernelGGL(k_pre1, dim3(3037), dim3(256), 0, stream,
                       inp, w1, w2, w3, ft0, wT1, wT2, wT3, Pmin1);
    hipLaunchKernelGGL(k_pre2, dim3(213), dim3(256), 0, stream,
                       ft0, wT2, wT3, Pmin1, zmap, PosS2, PosS3, m1);
    hipLaunchKernelGGL(k_pre3, dim3(185), dim3(256), 0, stream, PosS2, PosS3, W2e, W3s);

    hipLaunchKernelGGL(k_conv1f, dim3(900, NB), dim3(128), 0, stream, ft0, zmap, wT1, m1, ft1);
    hipLaunchKernelGGL(k_pool1c, dim3((NB * 17 * 17 * 90 + 255) / 256), dim3(256), 0, stream, ft1, ft1p);
    hipLaunchKernelGGL(k_conv2cr, dim3(169, NB), dim3(256), 0, stream, ft1p, wT2, W2e, ft2);
    hipLaunchKernelGGL(k_pool2c, dim3((NB * 8 * 8 * 250 + 255) / 256), dim3(256), 0, stream, ft2, ft2p);
    hipLaunchKernelGGL(k_conv3cr, dim3(16, NB), dim3(256), 0, stream, ft2p, wT3, W3s, out);
    hipLaunchKernelGGL(k_winner, dim3(NB), dim3(256), 0, stream, out, out);
}